// Round 5
// baseline (227.178 us; speedup 1.0000x reference)
//
#include <hip/hip_runtime.h>
#include <hip/hip_fp16.h>
#include <cstdint>

#define CDIM 40
#define FDIM 128
#define BIN_SHIFT 8      // 256 nodes per bin
#define BIN_SZ (1 << BIN_SHIFT)
#define CHUNK 4096       // edges per binning chunk
#define STAGE_CAP 8192   // LDS-staged csr ints per bin (32KB)

typedef _Float16 f16x8 __attribute__((ext_vector_type(8)));
typedef float f32x4 __attribute__((ext_vector_type(4)));
typedef int i32x4 __attribute__((ext_vector_type(4)));
typedef float f32x4v __attribute__((ext_vector_type(4)));

static __device__ __forceinline__ long long load_idx(const void* p, int is64, long long i) {
    if (is64) return ((const long long*)p)[i];
    return (long long)((const int*)p)[i];
}

static __device__ __forceinline__ unsigned packh2(float a, float b) {
    __half2 h;
    h.x = __float2half(a);
    h.y = __float2half(b);
    return *(unsigned*)&h;
}

// add 8 fp16 values (one uint4) into acc[0..8)
static __device__ __forceinline__ void addv4(float* acc, uint4 v) {
    const __half2* h = (const __half2*)&v;
    float2 f0 = __half22float2(h[0]);
    float2 f1 = __half22float2(h[1]);
    float2 f2 = __half22float2(h[2]);
    float2 f3 = __half22float2(h[3]);
    acc[0] += f0.x; acc[1] += f0.y; acc[2] += f1.x; acc[3] += f1.y;
    acc[4] += f2.x; acc[5] += f2.y; acc[6] += f3.x; acc[7] += f3.y;
}

static __device__ __forceinline__ f16x8 cvt8(float4 a, float4 b) {
    f16x8 r;
    r[0] = (_Float16)a.x; r[1] = (_Float16)a.y; r[2] = (_Float16)a.z; r[3] = (_Float16)a.w;
    r[4] = (_Float16)b.x; r[5] = (_Float16)b.y; r[6] = (_Float16)b.z; r[7] = (_Float16)b.w;
    return r;
}

// Init capacity cursors + zero the sentinel row N of all four g tables
// (csr pad slots point at it).
__global__ void k_init(int* cursor, int nb, int capRec,
                       __half* gA0, __half* gB0, __half* gA1, __half* gB1, int N) {
    int i = blockIdx.x * blockDim.x + threadIdx.x;
    if (i < nb) cursor[i] = i * capRec;
    if (i < 40) {
        if (i < 16)      ((unsigned*)(gA0 + (size_t)N * 32))[i] = 0u;
        else if (i < 20) ((unsigned*)(gB0 + (size_t)N * 8))[i - 16] = 0u;
        else if (i < 36) ((unsigned*)(gA1 + (size_t)N * 32))[i - 20] = 0u;
        else             ((unsigned*)(gB1 + (size_t)N * 8))[i - 36] = 0u;
    }
}

// Binning scatter into capacity-laid-out bins. Inline int64-vs-int32 detect.
__global__ __launch_bounds__(256) void kA3(const void* ei, long long E,
                                           int nb, int* __restrict__ cursor,
                                           unsigned* __restrict__ binned) {
    __shared__ unsigned lval[CHUNK];
    __shared__ unsigned short lbin[CHUNK];
    __shared__ int lcnt[512];
    __shared__ int lbase[512];
    __shared__ int lflag;
    int tid = threadIdx.x;
    if (tid == 0) lflag = 1;
    for (int i = tid; i < nb; i += 256) lcnt[i] = 0;
    __syncthreads();
    {
        const unsigned* w = (const unsigned*)ei;
        int nscan = (int)((2 * E < 4096) ? (2 * E) : 4096);
        for (int k = 1 + 2 * tid; k < nscan; k += 512)
            if (w[k] != 0u) lflag = 0;
    }
    __syncthreads();
    int is64 = lflag;
    long long base = (long long)blockIdx.x * CHUNK;
    int nk = (int)min((long long)CHUNK, E - base);
    for (int k = tid; k < nk; k += 256) {
        long long e = base + k;
        int s = (int)load_idx(ei, is64, e);
        int d = (int)load_idx(ei, is64, E + e);
        int bin = d >> BIN_SHIFT;
        lval[k] = (unsigned)s | ((unsigned)(d & (BIN_SZ - 1)) << 17);
        lbin[k] = (unsigned short)bin;
        atomicAdd(&lcnt[bin], 1);
    }
    __syncthreads();
    for (int i = tid; i < nb; i += 256) {
        int c = lcnt[i];
        lbase[i] = c ? atomicAdd(&cursor[i], c) : 0;
        lcnt[i] = 0;
    }
    __syncthreads();
    for (int k = tid; k < nk; k += 256) {
        int bin = lbin[k];
        int loc = atomicAdd(&lcnt[bin], 1);
        binned[lbase[bin] + loc] = lval[k];
    }
}

// Fused pass B + GEMM: one block per bin (256 nodes).
// Build: per-node degree, dinv (LDS), degree-sorted meta {rowp, node|deg<<17},
// CSR segment (8-aligned lists, sentinel pads -> zero row N). Wave-shfl scans.
// Tail: MFMA gemm g[i,c] = fp16(dinv[i]*sum_f x[i,f]W[c,f]) for this bin's
// nodes, split-store gA[node][32ch] (64B rows) + gB[node][8ch] (16B rows).
__global__ __launch_bounds__(256) void kBG(const unsigned* __restrict__ binned,
                                           const int* __restrict__ cursor,
                                           int capRec, int capC,
                                           int2* __restrict__ meta,
                                           int* __restrict__ cursorG,
                                           int* __restrict__ csr,
                                           const float* __restrict__ x,
                                           const float* __restrict__ W,
                                           __half* __restrict__ gA,
                                           __half* __restrict__ gB, int N) {
    __shared__ int lcnt[BIN_SZ];
    __shared__ int lsum[4];
    __shared__ int dh[64];
    __shared__ float dinvL[BIN_SZ];
    __shared__ int stage[STAGE_CAP];
    int b = blockIdx.x, tid = threadIdx.x;
    const int wid = tid >> 6;
    const int lane = tid & 63;
    int node0 = b << BIN_SHIFT;
    int nn = min(BIN_SZ, N - node0);
    int recBase = b * capRec;
    int csrBase = b * capC;
    int nedges = cursor[b] - recBase;

    lcnt[tid] = 0;
    if (tid < 64) dh[tid] = 0;
    __syncthreads();
    for (int t = tid; t < nedges; t += 256)
        atomicAdd(&lcnt[(binned[recBase + t] >> 17) & (BIN_SZ - 1)], 1);
    __syncthreads();
    int myc = lcnt[tid];
    int psz = (myc + 7) & ~7;          // padded size (8-aligned for pipelined gather)
    // wave-level inclusive scan of psz (no barriers)
    int incl = psz;
#pragma unroll
    for (int off = 1; off < 64; off <<= 1) {
        int up = __shfl_up(incl, off, 64);
        if (lane >= off) incl += up;
    }
    if (lane == 63) lsum[wid] = incl;
    if (tid < nn) {
        dinvL[tid] = rsqrtf(1.0f + (float)myc);
        atomicAdd(&dh[min(myc, 63)], 1);
    } else {
        dinvL[tid] = 0.0f;
    }
    __syncthreads();
    int woff = 0;
#pragma unroll
    for (int w = 0; w < 4; ++w) woff += (w < wid) ? lsum[w] : 0;
    int ex = woff + incl - psz;        // 8-aligned start within bin
    int total = lsum[0] + lsum[1] + lsum[2] + lsum[3];
    // exclusive scan of the 64 degree buckets: wave 0, shfl
    if (wid == 0) {
        int dv = dh[lane];
        int di = dv;
#pragma unroll
        for (int off = 1; off < 64; off <<= 1) {
            int up = __shfl_up(di, off, 64);
            if (lane >= off) di += up;
        }
        dh[lane] = di - dv;
    }
    __syncthreads();
    // degree-sorted permuted meta (ascending degree within bin)
    if (tid < nn) {
        int pos = atomicAdd(&dh[min(myc, 63)], 1);
        int2 mi;
        mi.x = csrBase + ex;
        mi.y = (node0 + tid) | (myc << 17);
        meta[node0 + pos] = mi;
    }
    __syncthreads();
    lcnt[tid] = ex;                    // scatter cursors (real-entry start)
    __syncthreads();
    if (total <= STAGE_CAP) {
        // prefill with sentinel N (covers pad slots)
        for (int t = tid; t < total; t += 256) stage[t] = N;
        __syncthreads();
        for (int t = tid; t < nedges; t += 256) {
            unsigned v = binned[recBase + t];
            int src = (int)(v & 0x1FFFFu);
            int dl  = (int)((v >> 17) & (BIN_SZ - 1));
            int p = atomicAdd(&lcnt[dl], 1);
            stage[p] = src;
        }
        __syncthreads();
        const int4* sp = (const int4*)stage;
        int4* cp = (int4*)(csr + csrBase);
        for (int t = tid; t < (total >> 2); t += 256) cp[t] = sp[t];
    } else {
        // overflow fallback (never hit for random graphs): global cursors
        if (tid < nn) cursorG[node0 + tid] = csrBase + ex;
        __syncthreads();
        for (int t = tid; t < nedges; t += 256) {
            unsigned v = binned[recBase + t];
            int src = (int)(v & 0x1FFFFu);
            int dl  = (int)((v >> 17) & (BIN_SZ - 1));
            int p = atomicAdd(&cursorG[node0 + dl], 1);
            csr[p] = src;
        }
        if (tid < nn)
            for (int k = myc; k < psz; ++k) csr[csrBase + ex + k] = N;
    }
    __syncthreads();

    // ---- fused MFMA gemm for this bin's 256 nodes ----
    const int m = lane & 15;
    const int quad = lane >> 4;
    f16x8 bfrag[3][4];
#pragma unroll
    for (int t = 0; t < 3; ++t) {
        int c = t * 16 + m;
#pragma unroll
        for (int q = 0; q < 4; ++q) {
            if (c < CDIM) {
                const float* wp = W + (size_t)c * FDIM + q * 32 + quad * 8;
                float4 w0 = *(const float4*)wp;
                float4 w1 = *(const float4*)(wp + 4);
                bfrag[t][q] = cvt8(w0, w1);
            } else {
                f16x8 z = {0, 0, 0, 0, 0, 0, 0, 0};
                bfrag[t][q] = z;
            }
        }
    }
#pragma unroll
    for (int i = 0; i < 4; ++i) {
        int lnode = wid * 64 + i * 16;
        int nodebase = node0 + lnode;
        if (nodebase >= N) break;
        const float* xp = x + (size_t)(nodebase + m) * FDIM + quad * 8;
        f16x8 afrag[4];
#pragma unroll
        for (int q = 0; q < 4; ++q) {
            float4 x0 = *(const float4*)(xp + q * 32);
            float4 x1 = *(const float4*)(xp + q * 32 + 4);
            afrag[q] = cvt8(x0, x1);
        }
        f32x4 acc0 = {0, 0, 0, 0}, acc1 = {0, 0, 0, 0}, acc2 = {0, 0, 0, 0};
#pragma unroll
        for (int q = 0; q < 4; ++q) {
            acc0 = __builtin_amdgcn_mfma_f32_16x16x32_f16(afrag[q], bfrag[0][q], acc0, 0, 0, 0);
            acc1 = __builtin_amdgcn_mfma_f32_16x16x32_f16(afrag[q], bfrag[1][q], acc1, 0, 0, 0);
            acc2 = __builtin_amdgcn_mfma_f32_16x16x32_f16(afrag[q], bfrag[2][q], acc2, 0, 0, 0);
        }
        float ds[4];
#pragma unroll
        for (int r = 0; r < 4; ++r) ds[r] = dinvL[lnode + quad * 4 + r];
#pragma unroll
        for (int r = 0; r < 4; ++r) {
            int node = nodebase + quad * 4 + r;
            gA[(size_t)node * 32 + m]      = __float2half(acc0[r] * ds[r]);
            gA[(size_t)node * 32 + 16 + m] = __float2half(acc1[r] * ds[r]);
            if (m < 8)
                gB[(size_t)node * 8 + m]   = __float2half(acc2[r] * ds[r]);
        }
    }
}

// One hop in g-space, 5 lanes per node: lane = (gidx, 8-ch chunk), 16B uint4
// per edge per lane. c<4 read gA (64B rows; 4 lanes coalesce to one line),
// c=4 reads gB (1.6MB, L2-resident). csr lists are 8-aligned (pads -> zero
// sentinel row N), walked with a 2-stage software pipeline: two 4-edge load
// groups alternate in flight and the next two csr quads are prefetched a
// stage ahead, so the memory pipe never drains between batches (the R0-R4
// loop drained vmcnt to 0 every 8 edges -> ~40% duty-cycle loss).
// csr/meta reads are nontemporal (evict-first; protect the random table).
// mode 0: write split fp16 tables; mode 1: nt fp32 out + bias.
__global__ __launch_bounds__(256) void k_gather(const int2* __restrict__ meta,
                                                const int* __restrict__ csr,
                                                const __half* __restrict__ gA,
                                                const __half* __restrict__ gB,
                                                const float* __restrict__ b,
                                                __half* __restrict__ goA,
                                                __half* __restrict__ goB,
                                                float* __restrict__ outF,
                                                int N, int mode) {
    unsigned t = blockIdx.x * 256 + threadIdx.x;
    unsigned gidx = t / 5, c = t - gidx * 5;
    if (gidx >= (unsigned)N) return;
    int2 mi = meta[gidx];
    int node = mi.y & 0x1FFFF;
    int deg = mi.y >> 17;
    int len = (deg + 7) & ~7;
    const int* cp = csr + mi.x;
    const uint4* src;
    unsigned stride;
    if (c < 4) { src = (const uint4*)gA + c; stride = 4; }
    else       { src = (const uint4*)gB;     stride = 1; }
    float acc[8] = {0, 0, 0, 0, 0, 0, 0, 0};
    addv4(acc, src[(size_t)node * stride]);   // self-loop first (order fixed)
    if (len) {
        i32x4 ca = __builtin_nontemporal_load((const i32x4*)cp);
        i32x4 cb = __builtin_nontemporal_load((const i32x4*)(cp + 4));
        uint4 t0 = src[(size_t)ca.x * stride];
        uint4 t1 = src[(size_t)ca.y * stride];
        uint4 t2 = src[(size_t)ca.z * stride];
        uint4 t3 = src[(size_t)ca.w * stride];
        int g = 8;
        for (; g < len; g += 8) {
            i32x4 cc = __builtin_nontemporal_load((const i32x4*)(cp + g));
            uint4 u0 = src[(size_t)cb.x * stride];
            uint4 u1 = src[(size_t)cb.y * stride];
            uint4 u2 = src[(size_t)cb.z * stride];
            uint4 u3 = src[(size_t)cb.w * stride];
            addv4(acc, t0); addv4(acc, t1); addv4(acc, t2); addv4(acc, t3);
            i32x4 cd = __builtin_nontemporal_load((const i32x4*)(cp + g + 4));
            t0 = src[(size_t)cc.x * stride];
            t1 = src[(size_t)cc.y * stride];
            t2 = src[(size_t)cc.z * stride];
            t3 = src[(size_t)cc.w * stride];
            addv4(acc, u0); addv4(acc, u1); addv4(acc, u2); addv4(acc, u3);
            cb = cd;
        }
        // tail: t-group in flight, cb resolved but unissued
        uint4 u0 = src[(size_t)cb.x * stride];
        uint4 u1 = src[(size_t)cb.y * stride];
        uint4 u2 = src[(size_t)cb.z * stride];
        uint4 u3 = src[(size_t)cb.w * stride];
        addv4(acc, t0); addv4(acc, t1); addv4(acc, t2); addv4(acc, t3);
        addv4(acc, u0); addv4(acc, u1); addv4(acc, u2); addv4(acc, u3);
    }
    float d = rsqrtf(1.0f + (float)deg);
    if (mode == 0) {
        float s = d * d;
        uint4 o;
        o.x = packh2(acc[0] * s, acc[1] * s);
        o.y = packh2(acc[2] * s, acc[3] * s);
        o.z = packh2(acc[4] * s, acc[5] * s);
        o.w = packh2(acc[6] * s, acc[7] * s);
        if (c < 4) ((uint4*)goA)[(size_t)node * 4 + c] = o;
        else       ((uint4*)goB)[(size_t)node] = o;
    } else {
        float4 bv0 = ((const float4*)b)[2 * c];
        float4 bv1 = ((const float4*)b)[2 * c + 1];
        f32x4v o0, o1;
        o0[0] = acc[0] * d + bv0.x;
        o0[1] = acc[1] * d + bv0.y;
        o0[2] = acc[2] * d + bv0.z;
        o0[3] = acc[3] * d + bv0.w;
        o1[0] = acc[4] * d + bv1.x;
        o1[1] = acc[5] * d + bv1.y;
        o1[2] = acc[6] * d + bv1.z;
        o1[3] = acc[7] * d + bv1.w;
        __builtin_nontemporal_store(o0, (f32x4v*)outF + (size_t)node * 10 + 2 * c);
        __builtin_nontemporal_store(o1, (f32x4v*)outF + (size_t)node * 10 + 2 * c + 1);
    }
}

static inline size_t align256(size_t v) { return (v + 255) & ~(size_t)255; }

extern "C" void kernel_launch(void* const* d_in, const int* in_sizes, int n_in,
                              void* d_out, int out_size, void* d_ws, size_t ws_size,
                              hipStream_t stream) {
    const float* x  = (const float*)d_in[0];
    const void*  ei = d_in[1];
    const float* W  = (const float*)d_in[2];
    const float* b  = (const float*)d_in[3];
    float* out = (float*)d_out;

    const int N = in_sizes[0] / FDIM;                 // 100000
    const long long E = (long long)in_sizes[1] / 2;   // 1600000

    const int nb     = (N + BIN_SZ - 1) >> BIN_SHIFT;        // 391 bins
    const int nchunk = (int)((E + CHUNK - 1) / CHUNK);       // 391 chunks
    int capRec = (int)(E / nb) + 2048;                       // record capacity
    if (capRec > STAGE_CAP) capRec = STAGE_CAP;
    int capC = (capRec + BIN_SZ * 7 + 1031) & ~7;            // csr capacity (8-pads)

    char* wsb = (char*)d_ws;
    size_t off = 0;
    int*      cursor  = (int*)(wsb + off);      off = align256(off + (size_t)nb * 4);
    int*      cursorG = (int*)(wsb + off);      off = align256(off + (size_t)N * 4);
    int2*     meta    = (int2*)(wsb + off);     off = align256(off + (size_t)N * 8);
    __half*   gA0     = (__half*)(wsb + off);   off = align256(off + (size_t)(N + 1) * 32 * 2);
    __half*   gB0     = (__half*)(wsb + off);   off = align256(off + (size_t)(N + 1) * 8 * 2);
    __half*   gA1     = (__half*)(wsb + off);   off = align256(off + (size_t)(N + 1) * 32 * 2);
    __half*   gB1     = (__half*)(wsb + off);   off = align256(off + (size_t)(N + 1) * 8 * 2);
    unsigned* binned  = (unsigned*)(wsb + off); off = align256(off + (size_t)nb * capRec * 4);
    int*      csr     = (int*)(wsb + off);      off = align256(off + (size_t)nb * capC * 4);

    const int B = 256;
    const unsigned GT = 5u * (unsigned)N;
    const int nbGA = (int)((GT + B - 1) / B);

    k_init  <<<(nb + 255) / 256, 256, 0, stream>>>(cursor, nb, capRec, gA0, gB0, gA1, gB1, N);
    kA3     <<<nchunk, B, 0, stream>>>(ei, E, nb, cursor, binned);
    kBG     <<<nb, B, 0, stream>>>(binned, cursor, capRec, capC, meta, cursorG, csr,
                                   x, W, gA0, gB0, N);
    k_gather<<<nbGA, B, 0, stream>>>(meta, csr, gA0, gB0, b, gA1, gB1, nullptr, N, 0);
    k_gather<<<nbGA, B, 0, stream>>>(meta, csr, gA1, gB1, b, nullptr, nullptr, out, N, 1);
}